// Round 1
// baseline (548.774 us; speedup 1.0000x reference)
//
#include <hip/hip_runtime.h>

#define NB 8
#define NNODE 10000
#define NEDGE 160000
#define HID 128
#define TIN 12
#define FLAT 24
#define MROWS (NNODE * NB)   // 80000
#define EPSBN 1e-5f

// ---------------------------------------------------------------------------
// degree histogram (int atomics)
__global__ void deg_kernel(const int* __restrict__ ei, int* __restrict__ degi) {
    int e = blockIdx.x * blockDim.x + threadIdx.x;
    if (e < NEDGE) atomicAdd(&degi[ei[NEDGE + e]], 1);
}

// single-block scan: row_ptr (exclusive prefix over deg) + inv_deg
__global__ __launch_bounds__(1024) void scan_kernel(const int* __restrict__ degi,
                                                    int* __restrict__ row_ptr,
                                                    float* __restrict__ inv_deg) {
    __shared__ int sdata[1024];
    const int t = threadIdx.x;
    const int CH = 10;                 // 1024*10 >= 10000
    const int i0 = t * CH;
    int sum = 0;
    for (int i = i0; i < i0 + CH && i < NNODE; ++i) sum += degi[i];
    sdata[t] = sum;
    for (int off = 1; off < 1024; off <<= 1) {
        __syncthreads();
        int v = (t >= off) ? sdata[t - off] : 0;
        __syncthreads();
        sdata[t] += v;
    }
    __syncthreads();
    int run = sdata[t] - sum;          // exclusive base
    for (int i = i0; i < i0 + CH && i < NNODE; ++i) {
        row_ptr[i] = run;
        int d = degi[i];
        run += d;
        inv_deg[i] = 1.0f / (float)max(d, 1);
    }
    if (t == 1023) row_ptr[NNODE] = sdata[1023];
}

__global__ void csr_fill(const int* __restrict__ ei, const int* __restrict__ row_ptr,
                         int* __restrict__ cursor, int* __restrict__ csr_src) {
    int e = blockIdx.x * blockDim.x + threadIdx.x;
    if (e < NEDGE) {
        int d = ei[NEDGE + e];
        int pos = atomicAdd(&cursor[d], 1);
        csr_src[row_ptr[d] + pos] = ei[e];
    }
}

// x (B,T,N,2) -> X0[(n*8+b)][24 + t*2 + c], X0 stride 48
__global__ void transpose_x(const float* __restrict__ x, float* __restrict__ X0) {
    int id = blockIdx.x * 256 + threadIdx.x;       // over B*T*N
    if (id >= NB * TIN * NNODE) return;
    int n = id % NNODE;
    int bt = id / NNODE;
    int b = bt / TIN, tt = bt % TIN;
    float2 v = *(const float2*)&x[(size_t)id * 2];
    *(float2*)&X0[(n * NB + b) * 48 + 24 + tt * 2] = v;
}

// build BN-folded concatenated weights + biases
__global__ void prep_weights(const float* __restrict__ Wl0, const float* __restrict__ Wr0,
                             const float* __restrict__ bl0, const float* __restrict__ Wl12,
                             const float* __restrict__ Wr12, const float* __restrict__ bl12,
                             const float* __restrict__ g, const float* __restrict__ bb,
                             const float* __restrict__ m, const float* __restrict__ v,
                             float* __restrict__ W0c, float* __restrict__ W1c,
                             float* __restrict__ W2c, float* __restrict__ bias012) {
    int r = blockIdx.x, j = threadIdx.x;
    if (r < 48) {
        float s = g[j] / sqrtf(v[j] + EPSBN);
        float val = (r < 24) ? Wl0[r * 128 + j] : Wr0[(r - 24) * 128 + j];
        W0c[r * 128 + j] = val * s;
    } else if (r < 304) {
        int rr = r - 48;
        float s = g[128 + j] / sqrtf(v[128 + j] + EPSBN);
        float val = (rr < 128) ? Wl12[rr * 128 + j] : Wr12[(rr - 128) * 128 + j];
        W1c[rr * 128 + j] = val * s;
    } else if (r < 560) {
        int rr = r - 304;
        float s = g[256 + j] / sqrtf(v[256 + j] + EPSBN);
        float val = (rr < 128) ? Wl12[128 * 128 + rr * 128 + j]
                               : Wr12[128 * 128 + (rr - 128) * 128 + j];
        W2c[rr * 128 + j] = val * s;
    } else {
        int l = r - 560;   // 0..2
        float s = g[l * 128 + j] / sqrtf(v[l * 128 + j] + EPSBN);
        float blv = (l == 0) ? bl0[j] : bl12[(l - 1) * 128 + j];
        bias012[l * 128 + j] = blv * s + bb[l * 128 + j] - m[l * 128 + j] * s;
    }
}

// mean-aggregation, K=24, X0 stride 48 (h at col 24, mean at col 0)
__global__ __launch_bounds__(192) void agg24(float* __restrict__ X0,
                                             const int* __restrict__ row_ptr,
                                             const int* __restrict__ csr_src,
                                             const float* __restrict__ inv_deg) {
    int n = blockIdx.x;
    int t = threadIdx.x;              // 192 = 8*24
    int b = t / 24, k = t % 24;
    int p0 = row_ptr[n], p1 = row_ptr[n + 1];
    float acc = 0.0f;
    for (int p = p0; p < p1; ++p) {
        int s = csr_src[p];
        acc += X0[(s * NB + b) * 48 + 24 + k];
    }
    X0[(n * NB + b) * 48 + k] = acc * inv_deg[n];
}

// mean-aggregation, K=128, X stride 256 (h at col 128, mean at col 0)
__global__ __launch_bounds__(256) void agg128(float* __restrict__ X,
                                              const int* __restrict__ row_ptr,
                                              const int* __restrict__ csr_src,
                                              const float* __restrict__ inv_deg) {
    int n = blockIdx.x;
    int t = threadIdx.x;
    int b = t >> 5, q = (t & 31) * 4;
    int p0 = row_ptr[n], p1 = row_ptr[n + 1];
    float ax = 0, ay = 0, az = 0, aw = 0;
    for (int p = p0; p < p1; ++p) {
        int s = csr_src[p];
        float4 vv = *(const float4*)&X[(s * NB + b) * 256 + 128 + q];
        ax += vv.x; ay += vv.y; az += vv.z; aw += vv.w;
    }
    float sc = inv_deg[n];
    float4 o = {ax * sc, ay * sc, az * sc, aw * sc};
    *(float4*)&X[(n * NB + b) * 256 + q] = o;
}

// fp32 GEMM: C(128-wide) = relu(A[M x K] @ W[K x 128] + bias), write at out+row*ldo+ooff
__global__ __launch_bounds__(256) void gemm_fused(const float* __restrict__ A, int lda, int K,
                                                  const float* __restrict__ W,
                                                  const float* __restrict__ bias,
                                                  float* __restrict__ out, int ldo, int ooff,
                                                  int do_relu) {
    __shared__ float As[16][132];
    __shared__ float Bs[16][132];
    const int t = threadIdx.x;
    const int tx = t & 15, ty = t >> 4;
    const int row0 = blockIdx.x * 128;
    const int ar = t >> 2, akq = (t & 3) * 4;
    const int bkr = t >> 5, bc4 = (t & 31) * 4;

    float acc[2][2][4][4];
    #pragma unroll
    for (int a = 0; a < 2; ++a)
        #pragma unroll
        for (int c = 0; c < 2; ++c)
            #pragma unroll
            for (int i = 0; i < 4; ++i)
                #pragma unroll
                for (int j = 0; j < 4; ++j) acc[a][c][i][j] = 0.0f;

    for (int kc = 0; kc < K; kc += 16) {
        float4 a0 = *(const float4*)(A + (row0 + ar) * lda + kc + akq);
        float4 a1 = *(const float4*)(A + (row0 + ar + 64) * lda + kc + akq);
        float4 b0 = *(const float4*)(W + (kc + bkr) * 128 + bc4);
        float4 b1 = *(const float4*)(W + (kc + bkr + 8) * 128 + bc4);
        __syncthreads();
        As[akq + 0][ar] = a0.x; As[akq + 1][ar] = a0.y;
        As[akq + 2][ar] = a0.z; As[akq + 3][ar] = a0.w;
        As[akq + 0][ar + 64] = a1.x; As[akq + 1][ar + 64] = a1.y;
        As[akq + 2][ar + 64] = a1.z; As[akq + 3][ar + 64] = a1.w;
        *(float4*)&Bs[bkr][bc4] = b0;
        *(float4*)&Bs[bkr + 8][bc4] = b1;
        __syncthreads();
        #pragma unroll
        for (int k = 0; k < 16; ++k) {
            float4 av0 = *(const float4*)&As[k][ty * 4];
            float4 av1 = *(const float4*)&As[k][ty * 4 + 64];
            float4 bv0 = *(const float4*)&Bs[k][tx * 4];
            float4 bv1 = *(const float4*)&Bs[k][tx * 4 + 64];
            float a_[2][4] = {{av0.x, av0.y, av0.z, av0.w}, {av1.x, av1.y, av1.z, av1.w}};
            float b_[2][4] = {{bv0.x, bv0.y, bv0.z, bv0.w}, {bv1.x, bv1.y, bv1.z, bv1.w}};
            #pragma unroll
            for (int rh = 0; rh < 2; ++rh)
                #pragma unroll
                for (int i = 0; i < 4; ++i)
                    #pragma unroll
                    for (int ch = 0; ch < 2; ++ch)
                        #pragma unroll
                        for (int j = 0; j < 4; ++j)
                            acc[rh][ch][i][j] = fmaf(a_[rh][i], b_[ch][j], acc[rh][ch][i][j]);
        }
    }

    #pragma unroll
    for (int rh = 0; rh < 2; ++rh)
        #pragma unroll
        for (int i = 0; i < 4; ++i) {
            int gr = row0 + rh * 64 + ty * 4 + i;
            #pragma unroll
            for (int ch = 0; ch < 2; ++ch) {
                int c0 = ch * 64 + tx * 4;
                float4 bv = *(const float4*)(bias + c0);
                float4 v;
                v.x = acc[rh][ch][i][0] + bv.x;
                v.y = acc[rh][ch][i][1] + bv.y;
                v.z = acc[rh][ch][i][2] + bv.z;
                v.w = acc[rh][ch][i][3] + bv.w;
                if (do_relu) {
                    v.x = fmaxf(v.x, 0.0f); v.y = fmaxf(v.y, 0.0f);
                    v.z = fmaxf(v.z, 0.0f); v.w = fmaxf(v.w, 0.0f);
                }
                *(float4*)(out + gr * ldo + ooff + c0) = v;
            }
        }
}

// head: out = H3[M x 128] @ headW[128 x 24] + headb, scattered to (B,T,N,2) layout
__global__ __launch_bounds__(256) void head_kernel(const float* __restrict__ H3,
                                                   const float* __restrict__ hW,
                                                   const float* __restrict__ hb,
                                                   float* __restrict__ out) {
    __shared__ float Ws[128 * 24];
    __shared__ float bs[24];
    int t = threadIdx.x;
    for (int i = t; i < 128 * 24; i += 256) Ws[i] = hW[i];
    if (t < 24) bs[t] = hb[t];
    __syncthreads();
    int row = blockIdx.x * 256 + t;
    if (row >= MROWS) return;
    float acc[24];
    #pragma unroll
    for (int c = 0; c < 24; ++c) acc[c] = bs[c];
    const float* a = &H3[row * 128];
    #pragma unroll 2
    for (int kq = 0; kq < 32; ++kq) {
        float4 av = *(const float4*)&a[kq * 4];
        #pragma unroll
        for (int c = 0; c < 24; ++c) {
            acc[c] += av.x * Ws[(kq * 4 + 0) * 24 + c];
            acc[c] += av.y * Ws[(kq * 4 + 1) * 24 + c];
            acc[c] += av.z * Ws[(kq * 4 + 2) * 24 + c];
            acc[c] += av.w * Ws[(kq * 4 + 3) * 24 + c];
        }
    }
    int n = row >> 3, b = row & 7;
    #pragma unroll
    for (int tt = 0; tt < 12; ++tt) {
        float2 o;
        o.x = acc[tt * 2 + 0];
        o.y = acc[tt * 2 + 1];
        *(float2*)&out[((b * TIN + tt) * NNODE + n) * 2] = o;
    }
}

// ---------------------------------------------------------------------------
extern "C" void kernel_launch(void* const* d_in, const int* in_sizes, int n_in,
                              void* d_out, int out_size, void* d_ws, size_t ws_size,
                              hipStream_t stream) {
    const float* x      = (const float*)d_in[0];
    const int*   ei     = (const int*)d_in[1];
    const float* Wl0    = (const float*)d_in[2];
    const float* Wr0    = (const float*)d_in[3];
    const float* bl0    = (const float*)d_in[4];
    const float* Wl12   = (const float*)d_in[5];
    const float* Wr12   = (const float*)d_in[6];
    const float* bl12   = (const float*)d_in[7];
    const float* bn_g   = (const float*)d_in[8];
    const float* bn_b   = (const float*)d_in[9];
    const float* bn_m   = (const float*)d_in[10];
    const float* bn_v   = (const float*)d_in[11];
    const float* headW  = (const float*)d_in[12];
    const float* headb  = (const float*)d_in[13];
    float* out = (float*)d_out;

    float* ws = (float*)d_ws;
    float* X1 = ws;                                  // M x 256 (mean | h)
    float* X2 = X1 + (size_t)MROWS * 256;            // M x 256
    float* X0 = X2 + (size_t)MROWS * 256;            // M x 48 (mean | h)
    float* W0c = X0 + (size_t)MROWS * 48;            // 48 x 128
    float* W1c = W0c + 48 * 128;                     // 256 x 128
    float* W2c = W1c + 256 * 128;                    // 256 x 128
    float* bias012 = W2c + 256 * 128;                // 3 x 128
    float* inv_deg = bias012 + 3 * 128;              // N
    int* degi    = (int*)(inv_deg + NNODE);          // N
    int* row_ptr = degi + NNODE;                     // N+1
    int* cursor  = row_ptr + (NNODE + 1);            // N
    int* csr_src = cursor + NNODE;                   // E
    float* H3 = X1;                                  // alias (X1 dead after layer-1 GEMM)

    hipMemsetAsync(degi, 0, sizeof(int) * NNODE, stream);
    hipMemsetAsync(cursor, 0, sizeof(int) * NNODE, stream);

    deg_kernel<<<(NEDGE + 255) / 256, 256, 0, stream>>>(ei, degi);
    scan_kernel<<<1, 1024, 0, stream>>>(degi, row_ptr, inv_deg);
    csr_fill<<<(NEDGE + 255) / 256, 256, 0, stream>>>(ei, row_ptr, cursor, csr_src);
    transpose_x<<<(NB * TIN * NNODE + 255) / 256, 256, 0, stream>>>(x, X0);
    prep_weights<<<563, 128, 0, stream>>>(Wl0, Wr0, bl0, Wl12, Wr12, bl12,
                                          bn_g, bn_b, bn_m, bn_v, W0c, W1c, W2c, bias012);

    // layer 0
    agg24<<<NNODE, 192, 0, stream>>>(X0, row_ptr, csr_src, inv_deg);
    gemm_fused<<<MROWS / 128, 256, 0, stream>>>(X0, 48, 48, W0c, bias012, X1, 256, 128, 1);
    // layer 1
    agg128<<<NNODE, 256, 0, stream>>>(X1, row_ptr, csr_src, inv_deg);
    gemm_fused<<<MROWS / 128, 256, 0, stream>>>(X1, 256, 256, W1c, bias012 + 128, X2, 256, 128, 1);
    // layer 2
    agg128<<<NNODE, 256, 0, stream>>>(X2, row_ptr, csr_src, inv_deg);
    gemm_fused<<<MROWS / 128, 256, 0, stream>>>(X2, 256, 256, W2c, bias012 + 256, H3, 128, 0, 1);
    // head
    head_kernel<<<(MROWS + 255) / 256, 256, 0, stream>>>(H3, headW, headb, out);
}

// Round 3
// 341.296 us; speedup vs baseline: 1.6079x; 1.6079x over previous
//
#include <hip/hip_runtime.h>

#define NB 8
#define NNODE 10000
#define NEDGE 160000
#define HID 128
#define TIN 12
#define MROWS (NNODE * NB)   // 80000
#define EPSBN 1e-5f

typedef __attribute__((ext_vector_type(8))) short bf16x8;
typedef __attribute__((ext_vector_type(4))) float f32x4;
typedef unsigned short u16;

static __device__ __forceinline__ u16 f2bf(float f) {
    unsigned int u = __builtin_bit_cast(unsigned int, f);
    u = (u + 0x7fffu + ((u >> 16) & 1u)) >> 16;
    return (u16)u;
}
static __device__ __forceinline__ float bf2f(u16 h) {
    unsigned int u = ((unsigned int)h) << 16;
    return __builtin_bit_cast(float, u);
}

// ---------------------------------------------------------------------------
__global__ void deg_kernel(const int* __restrict__ ei, int* __restrict__ degi) {
    int e = blockIdx.x * blockDim.x + threadIdx.x;
    if (e < NEDGE) atomicAdd(&degi[ei[NEDGE + e]], 1);
}

__global__ __launch_bounds__(1024) void scan_kernel(const int* __restrict__ degi,
                                                    int* __restrict__ row_ptr,
                                                    float* __restrict__ inv_deg) {
    __shared__ int sdata[1024];
    const int t = threadIdx.x;
    const int CH = 10;
    const int i0 = t * CH;
    int sum = 0;
    for (int i = i0; i < i0 + CH && i < NNODE; ++i) sum += degi[i];
    sdata[t] = sum;
    for (int off = 1; off < 1024; off <<= 1) {
        __syncthreads();
        int v = (t >= off) ? sdata[t - off] : 0;
        __syncthreads();
        sdata[t] += v;
    }
    __syncthreads();
    int run = sdata[t] - sum;
    for (int i = i0; i < i0 + CH && i < NNODE; ++i) {
        row_ptr[i] = run;
        int d = degi[i];
        run += d;
        inv_deg[i] = 1.0f / (float)max(d, 1);
    }
    if (t == 1023) row_ptr[NNODE] = sdata[1023];
}

__global__ void csr_fill(const int* __restrict__ ei, const int* __restrict__ row_ptr,
                         int* __restrict__ cursor, int* __restrict__ csr_src) {
    int e = blockIdx.x * blockDim.x + threadIdx.x;
    if (e < NEDGE) {
        int d = ei[NEDGE + e];
        int pos = atomicAdd(&cursor[d], 1);
        csr_src[row_ptr[d] + pos] = ei[e];
    }
}

// x (B,T,N,2) fp32 -> X0[(n*8+b)][24 + t*2 + c] bf16, stride 64 (cols 48-63 stay 0)
__global__ void transpose_x(const float* __restrict__ x, u16* __restrict__ X0) {
    int id = blockIdx.x * 256 + threadIdx.x;
    if (id >= NB * TIN * NNODE) return;
    int n = id % NNODE;
    int bt = id / NNODE;
    int b = bt / TIN, tt = bt % TIN;
    float2 v = *(const float2*)&x[(size_t)id * 2];
    unsigned int packed = (unsigned int)f2bf(v.x) | ((unsigned int)f2bf(v.y) << 16);
    *(unsigned int*)&X0[(n * NB + b) * 64 + 24 + tt * 2] = packed;
}

// BN-folded, transposed, bf16 weights. grid 128 (c), 256 threads (k)
__global__ void prep_weights(const float* __restrict__ Wl0, const float* __restrict__ Wr0,
                             const float* __restrict__ bl0, const float* __restrict__ Wl12,
                             const float* __restrict__ Wr12, const float* __restrict__ bl12,
                             const float* __restrict__ g, const float* __restrict__ bb,
                             const float* __restrict__ m, const float* __restrict__ v,
                             u16* __restrict__ W0T, u16* __restrict__ W1T,
                             u16* __restrict__ W2T, float* __restrict__ bias012) {
    int c = blockIdx.x, k = threadIdx.x;
    float s0 = g[c] / sqrtf(v[c] + EPSBN);
    float s1 = g[128 + c] / sqrtf(v[128 + c] + EPSBN);
    float s2 = g[256 + c] / sqrtf(v[256 + c] + EPSBN);
    if (k < 64) {
        float val = (k < 24) ? Wl0[k * 128 + c] : ((k < 48) ? Wr0[(k - 24) * 128 + c] : 0.0f);
        W0T[c * 64 + k] = f2bf(val * s0);
    }
    float v1 = (k < 128) ? Wl12[k * 128 + c] : Wr12[(k - 128) * 128 + c];
    W1T[c * 256 + k] = f2bf(v1 * s1);
    float v2 = (k < 128) ? Wl12[128 * 128 + k * 128 + c] : Wr12[128 * 128 + (k - 128) * 128 + c];
    W2T[c * 256 + k] = f2bf(v2 * s2);
    if (k < 3) {
        float sl = g[k * 128 + c] / sqrtf(v[k * 128 + c] + EPSBN);
        float blv = (k == 0) ? bl0[c] : bl12[(k - 1) * 128 + c];
        bias012[k * 128 + c] = blv * sl + bb[k * 128 + c] - m[k * 128 + c] * sl;
    }
}

// mean-aggregation, K=24, X0 stride 64 bf16 (h at col 24, mean at col 0)
__global__ __launch_bounds__(192) void agg24(u16* __restrict__ X0,
                                             const int* __restrict__ row_ptr,
                                             const int* __restrict__ csr_src,
                                             const float* __restrict__ inv_deg) {
    int n = blockIdx.x;
    int t = threadIdx.x;
    int b = t / 24, k = t % 24;
    int p0 = row_ptr[n], p1 = row_ptr[n + 1];
    float acc = 0.0f;
    for (int p = p0; p < p1; ++p) {
        int s = csr_src[p];
        acc += bf2f(X0[(s * NB + b) * 64 + 24 + k]);
    }
    X0[(n * NB + b) * 64 + k] = f2bf(acc * inv_deg[n]);
}

// mean-aggregation, K=128, X stride 256 bf16 (h at col 128, mean at col 0)
__global__ __launch_bounds__(256) void agg128(u16* __restrict__ X,
                                              const int* __restrict__ row_ptr,
                                              const int* __restrict__ csr_src,
                                              const float* __restrict__ inv_deg) {
    int n = blockIdx.x;
    int t = threadIdx.x;
    int b = t >> 5, l = t & 31;
    int p0 = row_ptr[n], p1 = row_ptr[n + 1];
    float a0 = 0, a1 = 0, a2 = 0, a3 = 0;
    for (int p = p0; p < p1; ++p) {
        int s = csr_src[p];
        uint2 vv = *(const uint2*)&X[(s * NB + b) * 256 + 128 + l * 4];
        a0 += bf2f((u16)(vv.x & 0xffff));
        a1 += bf2f((u16)(vv.x >> 16));
        a2 += bf2f((u16)(vv.y & 0xffff));
        a3 += bf2f((u16)(vv.y >> 16));
    }
    float sc = inv_deg[n];
    uint2 o;
    o.x = (unsigned int)f2bf(a0 * sc) | ((unsigned int)f2bf(a1 * sc) << 16);
    o.y = (unsigned int)f2bf(a2 * sc) | ((unsigned int)f2bf(a3 * sc) << 16);
    *(uint2*)&X[(n * NB + b) * 256 + l * 4] = o;
}

// bf16 MFMA GEMM: out[row][ooff+col] = relu(A[M x K] @ WT^T + bias), N=128
// WT is [128 cols][K] row-major (pre-transposed). out bf16, ldo stride.
__global__ __launch_bounds__(256) void gemm_mfma(const u16* __restrict__ A, int lda, int K,
                                                 const u16* __restrict__ WT,
                                                 const float* __restrict__ bias,
                                                 u16* __restrict__ out, int ldo, int ooff) {
    __shared__ __align__(16) short As[128][72];
    __shared__ __align__(16) short Bs[128][72];
    const int t = threadIdx.x;
    const int row0 = blockIdx.x * 128;
    const int lane = t & 63, wid = t >> 6;
    const int wr = wid >> 1, wc = wid & 1;
    const int r16 = lane & 15, kg = lane >> 4;
    const int srow = t >> 3, scol = (t & 7) * 8;

    f32x4 acc[4][4];
    #pragma unroll
    for (int m = 0; m < 4; ++m)
        #pragma unroll
        for (int n = 0; n < 4; ++n)
            acc[m][n] = (f32x4){0.f, 0.f, 0.f, 0.f};

    for (int kc = 0; kc < K; kc += 64) {
        __syncthreads();
        #pragma unroll
        for (int p = 0; p < 4; ++p) {
            int r = p * 32 + srow;
            *(bf16x8*)&As[r][scol] =
                *(const bf16x8*)&A[(size_t)(row0 + r) * lda + kc + scol];
            *(bf16x8*)&Bs[r][scol] =
                *(const bf16x8*)&WT[(size_t)r * K + kc + scol];
        }
        __syncthreads();
        #pragma unroll
        for (int ks = 0; ks < 2; ++ks) {
            const int ko = ks * 32 + kg * 8;
            bf16x8 av[4], bv[4];
            #pragma unroll
            for (int m = 0; m < 4; ++m)
                av[m] = *(const bf16x8*)&As[wr * 64 + m * 16 + r16][ko];
            #pragma unroll
            for (int n = 0; n < 4; ++n)
                bv[n] = *(const bf16x8*)&Bs[wc * 64 + n * 16 + r16][ko];
            #pragma unroll
            for (int m = 0; m < 4; ++m)
                #pragma unroll
                for (int n = 0; n < 4; ++n)
                    acc[m][n] = __builtin_amdgcn_mfma_f32_16x16x32_bf16(
                        av[m], bv[n], acc[m][n], 0, 0, 0);
        }
    }

    #pragma unroll
    for (int m = 0; m < 4; ++m) {
        #pragma unroll
        for (int n = 0; n < 4; ++n) {
            int col = wc * 64 + n * 16 + r16;
            float bv = bias[col];
            #pragma unroll
            for (int r = 0; r < 4; ++r) {
                int grow = row0 + wr * 64 + m * 16 + kg * 4 + r;
                float val = fmaxf(acc[m][n][r] + bv, 0.0f);
                out[(size_t)grow * ldo + ooff + col] = f2bf(val);
            }
        }
    }
}

// head: out = H3[M x 128] bf16 @ headW[128 x 24] + headb, scatter to (B,T,N,2) fp32
__global__ __launch_bounds__(256) void head_kernel(const u16* __restrict__ H3,
                                                   const float* __restrict__ hW,
                                                   const float* __restrict__ hb,
                                                   float* __restrict__ out) {
    __shared__ float Ws[128 * 24];
    __shared__ float bs[24];
    int t = threadIdx.x;
    for (int i = t; i < 128 * 24; i += 256) Ws[i] = hW[i];
    if (t < 24) bs[t] = hb[t];
    __syncthreads();
    int row = blockIdx.x * 256 + t;
    if (row >= MROWS) return;
    float acc[24];
    #pragma unroll
    for (int c = 0; c < 24; ++c) acc[c] = bs[c];
    const u16* a = &H3[(size_t)row * 128];
    for (int kq = 0; kq < 16; ++kq) {
        bf16x8 raw = *(const bf16x8*)&a[kq * 8];
        #pragma unroll
        for (int j = 0; j < 8; ++j) {
            float av = bf2f((u16)raw[j]);
            #pragma unroll
            for (int c = 0; c < 24; ++c)
                acc[c] = fmaf(av, Ws[(kq * 8 + j) * 24 + c], acc[c]);
        }
    }
    int n = row >> 3, b = row & 7;
    #pragma unroll
    for (int tt = 0; tt < 12; ++tt) {
        float2 o;
        o.x = acc[tt * 2 + 0];
        o.y = acc[tt * 2 + 1];
        *(float2*)&out[((b * TIN + tt) * NNODE + n) * 2] = o;
    }
}

// ---------------------------------------------------------------------------
extern "C" void kernel_launch(void* const* d_in, const int* in_sizes, int n_in,
                              void* d_out, int out_size, void* d_ws, size_t ws_size,
                              hipStream_t stream) {
    const float* x      = (const float*)d_in[0];
    const int*   ei     = (const int*)d_in[1];
    const float* Wl0    = (const float*)d_in[2];
    const float* Wr0    = (const float*)d_in[3];
    const float* bl0    = (const float*)d_in[4];
    const float* Wl12   = (const float*)d_in[5];
    const float* Wr12   = (const float*)d_in[6];
    const float* bl12   = (const float*)d_in[7];
    const float* bn_g   = (const float*)d_in[8];
    const float* bn_b   = (const float*)d_in[9];
    const float* bn_m   = (const float*)d_in[10];
    const float* bn_v   = (const float*)d_in[11];
    const float* headW  = (const float*)d_in[12];
    const float* headb  = (const float*)d_in[13];
    float* out = (float*)d_out;

    u16* X0 = (u16*)d_ws;                            // M x 64
    u16* X1 = X0 + (size_t)MROWS * 64;               // M x 256 (mean | h)
    u16* X2 = X1 + (size_t)MROWS * 256;              // M x 256
    u16* W0T = X2 + (size_t)MROWS * 256;             // 128 x 64
    u16* W1T = W0T + 128 * 64;                       // 128 x 256
    u16* W2T = W1T + 128 * 256;                      // 128 x 256
    float* bias012 = (float*)(W2T + 128 * 256);      // 3 x 128
    float* inv_deg = bias012 + 3 * 128;              // N
    int* degi    = (int*)(inv_deg + NNODE);          // N
    int* row_ptr = degi + NNODE;                     // N+1
    int* cursor  = row_ptr + (NNODE + 1);            // N
    int* csr_src = cursor + NNODE;                   // E
    u16* H3 = X1;                                    // alias (X1 dead after layer-1 GEMM)

    hipMemsetAsync(X0, 0, (size_t)MROWS * 64 * sizeof(u16), stream);
    hipMemsetAsync(degi, 0, sizeof(int) * NNODE, stream);
    hipMemsetAsync(cursor, 0, sizeof(int) * NNODE, stream);

    deg_kernel<<<(NEDGE + 255) / 256, 256, 0, stream>>>(ei, degi);
    scan_kernel<<<1, 1024, 0, stream>>>(degi, row_ptr, inv_deg);
    csr_fill<<<(NEDGE + 255) / 256, 256, 0, stream>>>(ei, row_ptr, cursor, csr_src);
    transpose_x<<<(NB * TIN * NNODE + 255) / 256, 256, 0, stream>>>(x, X0);
    prep_weights<<<128, 256, 0, stream>>>(Wl0, Wr0, bl0, Wl12, Wr12, bl12,
                                          bn_g, bn_b, bn_m, bn_v, W0T, W1T, W2T, bias012);

    // layer 0
    agg24<<<NNODE, 192, 0, stream>>>(X0, row_ptr, csr_src, inv_deg);
    gemm_mfma<<<MROWS / 128, 256, 0, stream>>>(X0, 64, 64, W0T, bias012, X1, 256, 128);
    // layer 1
    agg128<<<NNODE, 256, 0, stream>>>(X1, row_ptr, csr_src, inv_deg);
    gemm_mfma<<<MROWS / 128, 256, 0, stream>>>(X1, 256, 256, W1T, bias012 + 128, X2, 256, 128);
    // layer 2
    agg128<<<NNODE, 256, 0, stream>>>(X2, row_ptr, csr_src, inv_deg);
    gemm_mfma<<<MROWS / 128, 256, 0, stream>>>(X2, 256, 256, W2T, bias012 + 256, H3, 128, 0);
    // head
    head_kernel<<<(MROWS + 255) / 256, 256, 0, stream>>>(H3, headW, headb, out);
}

// Round 4
// 322.383 us; speedup vs baseline: 1.7022x; 1.0587x over previous
//
#include <hip/hip_runtime.h>

#define NB 8
#define NNODE 10000
#define NEDGE 160000
#define MROWS 80000
#define TIN 12
#define EPSBN 1e-5f

typedef __attribute__((ext_vector_type(8))) short bf16x8;
typedef __attribute__((ext_vector_type(4))) float f32x4;
typedef unsigned short u16;
typedef unsigned int u32;

static __device__ __forceinline__ u16 f2bf(float f) {
    unsigned int u = __builtin_bit_cast(unsigned int, f);
    u = (u + 0x7fffu + ((u >> 16) & 1u)) >> 16;
    return (u16)u;
}
static __device__ __forceinline__ float bf2f(u16 h) {
    unsigned int u = ((unsigned int)h) << 16;
    return __builtin_bit_cast(float, u);
}

// ---------------------------------------------------------------------------
__global__ void deg_kernel(const int* __restrict__ ei, int* __restrict__ degi) {
    int e = blockIdx.x * blockDim.x + threadIdx.x;
    if (e < NEDGE) atomicAdd(&degi[ei[NEDGE + e]], 1);
}

// prefix scan over deg -> row_ptr, inv_deg; also zeroes cursor
__global__ __launch_bounds__(1024) void scan_kernel(const int* __restrict__ degi,
                                                    int* __restrict__ row_ptr,
                                                    float* __restrict__ inv_deg,
                                                    int* __restrict__ cursor) {
    __shared__ int sdata[1024];
    const int t = threadIdx.x;
    const int CH = 10;
    const int i0 = t * CH;
    int sum = 0;
    for (int i = i0; i < i0 + CH && i < NNODE; ++i) sum += degi[i];
    sdata[t] = sum;
    for (int off = 1; off < 1024; off <<= 1) {
        __syncthreads();
        int v = (t >= off) ? sdata[t - off] : 0;
        __syncthreads();
        sdata[t] += v;
    }
    __syncthreads();
    int run = sdata[t] - sum;
    for (int i = i0; i < i0 + CH && i < NNODE; ++i) {
        row_ptr[i] = run;
        int d = degi[i];
        run += d;
        inv_deg[i] = 1.0f / (float)max(d, 1);
        cursor[i] = 0;
    }
    if (t == 1023) row_ptr[NNODE] = sdata[1023];
}

__global__ void csr_fill(const int* __restrict__ ei, const int* __restrict__ row_ptr,
                         int* __restrict__ cursor, int* __restrict__ csr_src) {
    int e = blockIdx.x * blockDim.x + threadIdx.x;
    if (e < NEDGE) {
        int d = ei[NEDGE + e];
        int pos = atomicAdd(&cursor[d], 1);
        csr_src[row_ptr[d] + pos] = ei[e];
    }
}

// x (B,T,N,2) fp32 -> X0[(n*8+b)][24 + t*2 + c] bf16, stride 64 (cols 48-63 garbage;
// they multiply exact-zero W0T rows, so no memset needed)
__global__ void transpose_x(const float* __restrict__ x, u16* __restrict__ X0) {
    int id = blockIdx.x * 256 + threadIdx.x;
    if (id >= NB * TIN * NNODE) return;
    int n = id % NNODE;
    int bt = id / NNODE;
    int b = bt / TIN, tt = bt % TIN;
    float2 v = *(const float2*)&x[(size_t)id * 2];
    u32 packed = (u32)f2bf(v.x) | ((u32)f2bf(v.y) << 16);
    *(u32*)&X0[(n * NB + b) * 64 + 24 + tt * 2] = packed;
}

// BN-folded, transposed, bf16 weights. grid 128 (c), 256 threads (k)
__global__ void prep_weights(const float* __restrict__ Wl0, const float* __restrict__ Wr0,
                             const float* __restrict__ bl0, const float* __restrict__ Wl12,
                             const float* __restrict__ Wr12, const float* __restrict__ bl12,
                             const float* __restrict__ g, const float* __restrict__ bb,
                             const float* __restrict__ m, const float* __restrict__ v,
                             u16* __restrict__ W0T, u16* __restrict__ W1T,
                             u16* __restrict__ W2T, float* __restrict__ bias012) {
    int c = blockIdx.x, k = threadIdx.x;
    float s0 = g[c] / sqrtf(v[c] + EPSBN);
    float s1 = g[128 + c] / sqrtf(v[128 + c] + EPSBN);
    float s2 = g[256 + c] / sqrtf(v[256 + c] + EPSBN);
    if (k < 64) {
        float val = (k < 24) ? Wl0[k * 128 + c] : ((k < 48) ? Wr0[(k - 24) * 128 + c] : 0.0f);
        W0T[c * 64 + k] = f2bf(val * s0);
    }
    float v1 = (k < 128) ? Wl12[k * 128 + c] : Wr12[(k - 128) * 128 + c];
    W1T[c * 256 + k] = f2bf(v1 * s1);
    float v2 = (k < 128) ? Wl12[128 * 128 + k * 128 + c] : Wr12[128 * 128 + (k - 128) * 128 + c];
    W2T[c * 256 + k] = f2bf(v2 * s2);
    if (k < 3) {
        float sl = g[k * 128 + c] / sqrtf(v[k * 128 + c] + EPSBN);
        float blv = (k == 0) ? bl0[c] : bl12[(k - 1) * 128 + c];
        bias012[k * 128 + c] = blv * sl + bb[k * 128 + c] - m[k * 128 + c] * sl;
    }
}

// mean-aggregation K=24 on row-major X0 (stride 64): 2 nodes per block, u32 loads
__global__ __launch_bounds__(192) void agg24(u16* __restrict__ X0,
                                             const int* __restrict__ rp,
                                             const int* __restrict__ cs,
                                             const float* __restrict__ inv) {
    int u = threadIdx.x;
    int n = blockIdx.x * 2 + (u / 96);
    int w = u % 96;
    int b = w / 12, cp = w % 12;
    int p0 = rp[n], p1 = rp[n + 1];
    float a0 = 0, a1 = 0;
    for (int p = p0; p < p1; ++p) {
        int s = cs[p];
        u32 vv = *(const u32*)&X0[(s * NB + b) * 64 + 24 + cp * 2];
        a0 += bf2f((u16)(vv & 0xffff));
        a1 += bf2f((u16)(vv >> 16));
    }
    float sc = inv[n];
    u32 o = (u32)f2bf(a0 * sc) | ((u32)f2bf(a1 * sc) << 16);
    *(u32*)&X0[(n * NB + b) * 64 + cp * 2] = o;
}

// chunked mean-aggregation K=128: X layout [16 chunks][MROWS][16 cols],
// h in chunks 8..15, mean written to chunks 0..7.
// chunk = blockIdx.x & 7  -> XCD-pinned (round-robin dispatch), 2.56MB/chunk fits L2.
__global__ __launch_bounds__(64) void agg128c(u16* __restrict__ X,
                                              const int* __restrict__ rp,
                                              const int* __restrict__ cs,
                                              const float* __restrict__ inv) {
    int bid = blockIdx.x;
    int c = bid & 7;
    int n = bid >> 3;
    int t = threadIdx.x;
    int b = t >> 3, q = t & 7;
    int p0 = rp[n], p1 = rp[n + 1];
    const u16* hb = X + ((size_t)(8 + c) * MROWS) * 16;
    float a0 = 0, a1 = 0;
    for (int p = p0; p < p1; ++p) {
        int s = cs[p];
        u32 vv = *(const u32*)&hb[(s * NB + b) * 16 + q * 2];
        a0 += bf2f((u16)(vv & 0xffff));
        a1 += bf2f((u16)(vv >> 16));
    }
    float sc = inv[n];
    u32 o = (u32)f2bf(a0 * sc) | ((u32)f2bf(a1 * sc) << 16);
    *(u32*)&X[((size_t)c * MROWS + n * NB + b) * 16 + q * 2] = o;
}

// MFMA GEMM, M-tile 320 x N 128, 10 waves (wr 0..4, wc 0..1), W staged in LDS once,
// A-fragments loaded direct global->VGPR (no A LDS, no inner barriers).
// INC: A in chunked layout [K/16][MROWS][16]; else row-major lda=K.
// OUTC: write to chunked layout chunks 8..15; else row-major ld=128.
template<int K, bool INC, bool OUTC>
__global__ __launch_bounds__(640) void gemm_mfma(const u16* __restrict__ A,
                                                 const u16* __restrict__ WT,
                                                 const float* __restrict__ bias,
                                                 u16* __restrict__ out) {
    __shared__ __align__(16) short Bs[128][K + 8];
    const int t = threadIdx.x;
    const int row0 = blockIdx.x * 320;
    const int lane = t & 63, wid = t >> 6;
    const int wr = wid >> 1, wc = wid & 1;
    const int r16 = lane & 15, kg = lane >> 4;

    if (t < 512) {
        const int col = t >> 2, k0 = (t & 3) * (K / 4);
        #pragma unroll
        for (int j = 0; j < K / 32; ++j)
            *(bf16x8*)&Bs[col][k0 + j * 8] =
                *(const bf16x8*)&WT[col * K + k0 + j * 8];
    }
    __syncthreads();

    f32x4 acc[4][4];
    #pragma unroll
    for (int m = 0; m < 4; ++m)
        #pragma unroll
        for (int n = 0; n < 4; ++n)
            acc[m][n] = (f32x4){0.f, 0.f, 0.f, 0.f};

    const int rowbase = row0 + wr * 64 + r16;
    for (int kc = 0; kc < K; kc += 64) {
        #pragma unroll
        for (int ks = 0; ks < 2; ++ks) {
            const int k0 = kc + ks * 32 + kg * 8;
            bf16x8 av[4], bv[4];
            #pragma unroll
            for (int m = 0; m < 4; ++m) {
                int row = rowbase + m * 16;
                const u16* ap;
                if (INC)
                    ap = A + ((size_t)(k0 >> 4) * MROWS + row) * 16 + (k0 & 15);
                else
                    ap = A + (size_t)row * K + k0;
                av[m] = *(const bf16x8*)ap;
            }
            #pragma unroll
            for (int n = 0; n < 4; ++n)
                bv[n] = *(const bf16x8*)&Bs[wc * 64 + n * 16 + r16][k0];
            #pragma unroll
            for (int m = 0; m < 4; ++m)
                #pragma unroll
                for (int n = 0; n < 4; ++n)
                    acc[m][n] = __builtin_amdgcn_mfma_f32_16x16x32_bf16(
                        av[m], bv[n], acc[m][n], 0, 0, 0);
        }
    }

    #pragma unroll
    for (int m = 0; m < 4; ++m) {
        #pragma unroll
        for (int n = 0; n < 4; ++n) {
            int col = wc * 64 + n * 16 + r16;
            float bvf = bias[col];
            #pragma unroll
            for (int r = 0; r < 4; ++r) {
                int grow = row0 + wr * 64 + m * 16 + kg * 4 + r;
                float val = fmaxf(acc[m][n][r] + bvf, 0.0f);
                u16 h = f2bf(val);
                if (OUTC)
                    out[((size_t)(8 + wc * 4 + n) * MROWS + grow) * 16 + r16] = h;
                else
                    out[(size_t)grow * 128 + col] = h;
            }
        }
    }
}

// head: out = H3[M x 128] bf16 @ headW[128 x 24] + headb, scatter to (B,T,N,2) fp32
__global__ __launch_bounds__(256) void head_kernel(const u16* __restrict__ H3,
                                                   const float* __restrict__ hW,
                                                   const float* __restrict__ hb,
                                                   float* __restrict__ out) {
    __shared__ float Ws[128 * 24];
    __shared__ float bs[24];
    int t = threadIdx.x;
    for (int i = t; i < 128 * 24; i += 256) Ws[i] = hW[i];
    if (t < 24) bs[t] = hb[t];
    __syncthreads();
    int row = blockIdx.x * 256 + t;
    if (row >= MROWS) return;
    float acc[24];
    #pragma unroll
    for (int c = 0; c < 24; ++c) acc[c] = bs[c];
    const u16* a = &H3[(size_t)row * 128];
    for (int kq = 0; kq < 16; ++kq) {
        bf16x8 raw = *(const bf16x8*)&a[kq * 8];
        #pragma unroll
        for (int j = 0; j < 8; ++j) {
            float av = bf2f((u16)raw[j]);
            #pragma unroll
            for (int c = 0; c < 24; ++c)
                acc[c] = fmaf(av, Ws[(kq * 8 + j) * 24 + c], acc[c]);
        }
    }
    int n = row >> 3, b = row & 7;
    #pragma unroll
    for (int tt = 0; tt < 12; ++tt) {
        float2 o;
        o.x = acc[tt * 2 + 0];
        o.y = acc[tt * 2 + 1];
        *(float2*)&out[((b * TIN + tt) * NNODE + n) * 2] = o;
    }
}

// ---------------------------------------------------------------------------
extern "C" void kernel_launch(void* const* d_in, const int* in_sizes, int n_in,
                              void* d_out, int out_size, void* d_ws, size_t ws_size,
                              hipStream_t stream) {
    const float* x      = (const float*)d_in[0];
    const int*   ei     = (const int*)d_in[1];
    const float* Wl0    = (const float*)d_in[2];
    const float* Wr0    = (const float*)d_in[3];
    const float* bl0    = (const float*)d_in[4];
    const float* Wl12   = (const float*)d_in[5];
    const float* Wr12   = (const float*)d_in[6];
    const float* bl12   = (const float*)d_in[7];
    const float* bn_g   = (const float*)d_in[8];
    const float* bn_b   = (const float*)d_in[9];
    const float* bn_m   = (const float*)d_in[10];
    const float* bn_v   = (const float*)d_in[11];
    const float* headW  = (const float*)d_in[12];
    const float* headb  = (const float*)d_in[13];
    float* out = (float*)d_out;

    u16* X0 = (u16*)d_ws;                            // M x 64 row-major
    u16* X1 = X0 + (size_t)MROWS * 64;               // [16][M][16] chunked
    u16* X2 = X1 + (size_t)MROWS * 256;              // [16][M][16] chunked
    u16* W0T = X2 + (size_t)MROWS * 256;             // 128 x 64
    u16* W1T = W0T + 128 * 64;                       // 128 x 256
    u16* W2T = W1T + 128 * 256;                      // 128 x 256
    float* bias012 = (float*)(W2T + 128 * 256);      // 3 x 128
    float* inv_deg = bias012 + 3 * 128;              // N
    int* degi    = (int*)(inv_deg + NNODE);          // N
    int* row_ptr = degi + NNODE;                     // N+1
    int* cursor  = row_ptr + (NNODE + 1);            // N
    int* csr_src = cursor + NNODE;                   // E
    u16* H3 = X1;                                    // alias (X1 dead after gemm1)

    hipMemsetAsync(degi, 0, sizeof(int) * NNODE, stream);

    deg_kernel<<<(NEDGE + 255) / 256, 256, 0, stream>>>(ei, degi);
    scan_kernel<<<1, 1024, 0, stream>>>(degi, row_ptr, inv_deg, cursor);
    csr_fill<<<(NEDGE + 255) / 256, 256, 0, stream>>>(ei, row_ptr, cursor, csr_src);
    transpose_x<<<(NB * TIN * NNODE + 255) / 256, 256, 0, stream>>>(x, X0);
    prep_weights<<<128, 256, 0, stream>>>(Wl0, Wr0, bl0, Wl12, Wr12, bl12,
                                          bn_g, bn_b, bn_m, bn_v, W0T, W1T, W2T, bias012);

    // layer 0
    agg24<<<NNODE / 2, 192, 0, stream>>>(X0, row_ptr, csr_src, inv_deg);
    gemm_mfma<64, false, true><<<250, 640, 0, stream>>>(X0, W0T, bias012, X1);
    // layer 1
    agg128c<<<NNODE * 8, 64, 0, stream>>>(X1, row_ptr, csr_src, inv_deg);
    gemm_mfma<256, true, true><<<250, 640, 0, stream>>>(X1, W1T, bias012 + 128, X2);
    // layer 2
    agg128c<<<NNODE * 8, 64, 0, stream>>>(X2, row_ptr, csr_src, inv_deg);
    gemm_mfma<256, true, false><<<250, 640, 0, stream>>>(X2, W2T, bias012 + 256, H3);
    // head
    head_kernel<<<(MROWS + 255) / 256, 256, 0, stream>>>(H3, headW, headb, out);
}

// Round 6
// 283.094 us; speedup vs baseline: 1.9385x; 1.1388x over previous
//
#include <hip/hip_runtime.h>

#define NB 8
#define NNODE 10000
#define NEDGE 160000
#define MROWS 80000
#define TIN 12
#define EPSBN 1e-5f

typedef __attribute__((ext_vector_type(8))) short bf16x8;
typedef __attribute__((ext_vector_type(4))) float f32x4;
typedef unsigned short u16;
typedef unsigned int u32;

static __device__ __forceinline__ u16 f2bf(float f) {
    unsigned int u = __builtin_bit_cast(unsigned int, f);
    u = (u + 0x7fffu + ((u >> 16) & 1u)) >> 16;
    return (u16)u;
}
static __device__ __forceinline__ float bf2f(u16 h) {
    unsigned int u = ((unsigned int)h) << 16;
    return __builtin_bit_cast(float, u);
}

// ---------------------------------------------------------------------------
// fused pre-stage: [0,3750) transpose_x | [3750,4375) deg | [4375,4503) prep
__global__ __launch_bounds__(256) void fused_pre(const float* __restrict__ x,
                                                 u16* __restrict__ X0,
                                                 const int* __restrict__ ei,
                                                 int* __restrict__ degi,
                                                 const float* __restrict__ Wl0,
                                                 const float* __restrict__ Wr0,
                                                 const float* __restrict__ bl0,
                                                 const float* __restrict__ Wl12,
                                                 const float* __restrict__ Wr12,
                                                 const float* __restrict__ bl12,
                                                 const float* __restrict__ g,
                                                 const float* __restrict__ bb,
                                                 const float* __restrict__ m,
                                                 const float* __restrict__ v,
                                                 u16* __restrict__ W0T, u16* __restrict__ W1T,
                                                 u16* __restrict__ W2T,
                                                 float* __restrict__ bias012) {
    int blk = blockIdx.x;
    if (blk < 3750) {
        int id = blk * 256 + threadIdx.x;
        if (id >= NB * TIN * NNODE) return;
        int n = id % NNODE;
        int bt = id / NNODE;
        int b = bt / TIN, tt = bt % TIN;
        float2 vv = *(const float2*)&x[(size_t)id * 2];
        u32 packed = (u32)f2bf(vv.x) | ((u32)f2bf(vv.y) << 16);
        *(u32*)&X0[(n * NB + b) * 64 + 24 + tt * 2] = packed;
    } else if (blk < 4375) {
        int e = (blk - 3750) * 256 + threadIdx.x;
        if (e < NEDGE) atomicAdd(&degi[ei[NEDGE + e]], 1);
    } else {
        int c = blk - 4375, k = threadIdx.x;
        float s0 = g[c] / sqrtf(v[c] + EPSBN);
        float s1 = g[128 + c] / sqrtf(v[128 + c] + EPSBN);
        float s2 = g[256 + c] / sqrtf(v[256 + c] + EPSBN);
        if (k < 64) {
            float val = (k < 24) ? Wl0[k * 128 + c] : ((k < 48) ? Wr0[(k - 24) * 128 + c] : 0.0f);
            W0T[c * 64 + k] = f2bf(val * s0);
        }
        float v1 = (k < 128) ? Wl12[k * 128 + c] : Wr12[(k - 128) * 128 + c];
        W1T[c * 256 + k] = f2bf(v1 * s1);
        float v2 = (k < 128) ? Wl12[128 * 128 + k * 128 + c]
                             : Wr12[128 * 128 + (k - 128) * 128 + c];
        W2T[c * 256 + k] = f2bf(v2 * s2);
        if (k < 3) {
            float sl = g[k * 128 + c] / sqrtf(v[k * 128 + c] + EPSBN);
            float blv = (k == 0) ? bl0[c] : bl12[(k - 1) * 128 + c];
            bias012[k * 128 + c] = blv * sl + bb[k * 128 + c] - m[k * 128 + c] * sl;
        }
    }
}

// prefix scan over deg -> row_ptr, inv_deg; also zeroes cursor
__global__ __launch_bounds__(1024) void scan_kernel(const int* __restrict__ degi,
                                                    int* __restrict__ row_ptr,
                                                    float* __restrict__ inv_deg,
                                                    int* __restrict__ cursor) {
    __shared__ int sdata[1024];
    const int t = threadIdx.x;
    const int CH = 10;
    const int i0 = t * CH;
    int sum = 0;
    for (int i = i0; i < i0 + CH && i < NNODE; ++i) sum += degi[i];
    sdata[t] = sum;
    for (int off = 1; off < 1024; off <<= 1) {
        __syncthreads();
        int vv = (t >= off) ? sdata[t - off] : 0;
        __syncthreads();
        sdata[t] += vv;
    }
    __syncthreads();
    int run = sdata[t] - sum;
    for (int i = i0; i < i0 + CH && i < NNODE; ++i) {
        row_ptr[i] = run;
        int d = degi[i];
        run += d;
        inv_deg[i] = 1.0f / (float)max(d, 1);
        cursor[i] = 0;
    }
    if (t == 1023) row_ptr[NNODE] = sdata[1023];
}

__global__ void csr_fill(const int* __restrict__ ei, const int* __restrict__ row_ptr,
                         int* __restrict__ cursor, int* __restrict__ csr_src) {
    int e = blockIdx.x * blockDim.x + threadIdx.x;
    if (e < NEDGE) {
        int d = ei[NEDGE + e];
        int pos = atomicAdd(&cursor[d], 1);
        csr_src[row_ptr[d] + pos] = ei[e];
    }
}

// mean-aggregation K=24 on row-major X0 (stride 64), 2 nodes/block, unroll-4
__global__ __launch_bounds__(192) void agg24(u16* __restrict__ X0,
                                             const int* __restrict__ rp,
                                             const int* __restrict__ cs,
                                             const float* __restrict__ inv) {
    int u = threadIdx.x;
    int n = blockIdx.x * 2 + (u / 96);
    int w = u % 96;
    int b = w / 12, cp = w % 12;
    int p0 = rp[n], p1 = rp[n + 1];
    float a0 = 0, a1 = 0, b0 = 0, b1 = 0, c0 = 0, c1 = 0, d0 = 0, d1 = 0;
    int p = p0;
    for (; p + 4 <= p1; p += 4) {
        int s0 = cs[p], s1 = cs[p + 1], s2 = cs[p + 2], s3 = cs[p + 3];
        u32 v0 = *(const u32*)&X0[(s0 * NB + b) * 64 + 24 + cp * 2];
        u32 v1 = *(const u32*)&X0[(s1 * NB + b) * 64 + 24 + cp * 2];
        u32 v2 = *(const u32*)&X0[(s2 * NB + b) * 64 + 24 + cp * 2];
        u32 v3 = *(const u32*)&X0[(s3 * NB + b) * 64 + 24 + cp * 2];
        a0 += bf2f((u16)(v0 & 0xffff)); a1 += bf2f((u16)(v0 >> 16));
        b0 += bf2f((u16)(v1 & 0xffff)); b1 += bf2f((u16)(v1 >> 16));
        c0 += bf2f((u16)(v2 & 0xffff)); c1 += bf2f((u16)(v2 >> 16));
        d0 += bf2f((u16)(v3 & 0xffff)); d1 += bf2f((u16)(v3 >> 16));
    }
    for (; p < p1; ++p) {
        int s = cs[p];
        u32 vv = *(const u32*)&X0[(s * NB + b) * 64 + 24 + cp * 2];
        a0 += bf2f((u16)(vv & 0xffff)); a1 += bf2f((u16)(vv >> 16));
    }
    float sc = inv[n];
    float r0 = (a0 + b0) + (c0 + d0), r1 = (a1 + b1) + (c1 + d1);
    u32 o = (u32)f2bf(r0 * sc) | ((u32)f2bf(r1 * sc) << 16);
    *(u32*)&X0[(n * NB + b) * 64 + cp * 2] = o;
}

// chunked mean-aggregation K=128: X layout [16 chunks][MROWS][16 cols],
// h in chunks 8..15, mean -> chunks 0..7. chunk = blockIdx&7 (XCD-pinned).
// unroll-4: 8 independent loads in flight per wave iteration.
__global__ __launch_bounds__(64) void agg128c(u16* __restrict__ X,
                                              const int* __restrict__ rp,
                                              const int* __restrict__ cs,
                                              const float* __restrict__ inv) {
    int bid = blockIdx.x;
    int c = bid & 7;
    int n = bid >> 3;
    int t = threadIdx.x;
    int b = t >> 3, q = t & 7;
    int p0 = rp[n], p1 = rp[n + 1];
    const u16* hb = X + ((size_t)(8 + c) * MROWS) * 16;
    float a0 = 0, a1 = 0, b0 = 0, b1 = 0, c0 = 0, c1 = 0, d0 = 0, d1 = 0;
    int p = p0;
    for (; p + 4 <= p1; p += 4) {
        int s0 = cs[p], s1 = cs[p + 1], s2 = cs[p + 2], s3 = cs[p + 3];
        u32 v0 = *(const u32*)&hb[(s0 * NB + b) * 16 + q * 2];
        u32 v1 = *(const u32*)&hb[(s1 * NB + b) * 16 + q * 2];
        u32 v2 = *(const u32*)&hb[(s2 * NB + b) * 16 + q * 2];
        u32 v3 = *(const u32*)&hb[(s3 * NB + b) * 16 + q * 2];
        a0 += bf2f((u16)(v0 & 0xffff)); a1 += bf2f((u16)(v0 >> 16));
        b0 += bf2f((u16)(v1 & 0xffff)); b1 += bf2f((u16)(v1 >> 16));
        c0 += bf2f((u16)(v2 & 0xffff)); c1 += bf2f((u16)(v2 >> 16));
        d0 += bf2f((u16)(v3 & 0xffff)); d1 += bf2f((u16)(v3 >> 16));
    }
    for (; p < p1; ++p) {
        int s = cs[p];
        u32 vv = *(const u32*)&hb[(s * NB + b) * 16 + q * 2];
        a0 += bf2f((u16)(vv & 0xffff)); a1 += bf2f((u16)(vv >> 16));
    }
    float sc = inv[n];
    float r0 = (a0 + b0) + (c0 + d0), r1 = (a1 + b1) + (c1 + d1);
    u32 o = (u32)f2bf(r0 * sc) | ((u32)f2bf(r1 * sc) << 16);
    *(u32*)&X[((size_t)c * MROWS + n * NB + b) * 16 + q * 2] = o;
}

// MFMA GEMM, M-tile 320 x N 128, 10 waves, W staged in LDS once, A direct
// global->VGPR with depth-1 prefetch (named double-buffer, all indices static).
#define LOADA(dst, stp) { \
    const int k0_ = (stp) * 32 + kg * 8; \
    _Pragma("unroll") \
    for (int m_ = 0; m_ < 4; ++m_) { \
        const int row_ = rowbase + m_ * 16; \
        const u16* ap_; \
        if (INC) ap_ = A + ((size_t)(k0_ >> 4) * MROWS + row_) * 16 + (k0_ & 15); \
        else     ap_ = A + (size_t)row_ * K + k0_; \
        dst[m_] = *(const bf16x8*)ap_; \
    } }

#define MFMAS(av, stp) { \
    const int k0_ = (stp) * 32 + kg * 8; \
    bf16x8 bv_[4]; \
    _Pragma("unroll") \
    for (int n_ = 0; n_ < 4; ++n_) \
        bv_[n_] = *(const bf16x8*)&Bs[wc * 64 + n_ * 16 + r16][k0_]; \
    _Pragma("unroll") \
    for (int m_ = 0; m_ < 4; ++m_) \
        _Pragma("unroll") \
        for (int n_ = 0; n_ < 4; ++n_) \
            acc[m_][n_] = __builtin_amdgcn_mfma_f32_16x16x32_bf16(av[m_], bv_[n_], acc[m_][n_], 0, 0, 0); }

template<int K, bool INC, bool OUTC>
__global__ __launch_bounds__(640) void gemm_mfma(const u16* __restrict__ A,
                                                 const u16* __restrict__ WT,
                                                 const float* __restrict__ bias,
                                                 u16* __restrict__ out) {
    constexpr int NSTEP = K / 32;
    __shared__ __align__(16) short Bs[128][K + 8];
    const int t = threadIdx.x;
    const int row0 = blockIdx.x * 320;
    const int lane = t & 63, wid = t >> 6;
    const int wr = wid >> 1, wc = wid & 1;
    const int r16 = lane & 15, kg = lane >> 4;

    if (t < 512) {
        const int col = t >> 2, k0 = (t & 3) * (K / 4);
        #pragma unroll
        for (int j = 0; j < K / 32; ++j)
            *(bf16x8*)&Bs[col][k0 + j * 8] =
                *(const bf16x8*)&WT[col * K + k0 + j * 8];
    }
    __syncthreads();

    f32x4 acc[4][4];
    #pragma unroll
    for (int m = 0; m < 4; ++m)
        #pragma unroll
        for (int n = 0; n < 4; ++n)
            acc[m][n] = (f32x4){0.f, 0.f, 0.f, 0.f};

    const int rowbase = row0 + wr * 64 + r16;

    bf16x8 avA[4], avB[4];
    LOADA(avA, 0)
    #pragma unroll
    for (int s2 = 0; s2 < NSTEP; s2 += 2) {
        if (s2 + 1 < NSTEP) LOADA(avB, s2 + 1)
        MFMAS(avA, s2)
        if (s2 + 2 < NSTEP) LOADA(avA, s2 + 2)
        if (s2 + 1 < NSTEP) MFMAS(avB, s2 + 1)
    }

    #pragma unroll
    for (int m = 0; m < 4; ++m) {
        #pragma unroll
        for (int n = 0; n < 4; ++n) {
            int col = wc * 64 + n * 16 + r16;
            float bvf = bias[col];
            #pragma unroll
            for (int r = 0; r < 4; ++r) {
                int grow = row0 + wr * 64 + m * 16 + kg * 4 + r;
                float val = fmaxf(acc[m][n][r] + bvf, 0.0f);
                u16 h = f2bf(val);
                if (OUTC)
                    out[((size_t)(8 + wc * 4 + n) * MROWS + grow) * 16 + r16] = h;
                else
                    out[(size_t)grow * 128 + col] = h;
            }
        }
    }
}

// head: out = H3[M x 128] bf16 @ headW[128 x 24] + headb, scatter to (B,T,N,2) fp32
__global__ __launch_bounds__(256) void head_kernel(const u16* __restrict__ H3,
                                                   const float* __restrict__ hW,
                                                   const float* __restrict__ hb,
                                                   float* __restrict__ out) {
    __shared__ float Ws[128 * 24];
    __shared__ float bs[24];
    int t = threadIdx.x;
    for (int i = t; i < 128 * 24; i += 256) Ws[i] = hW[i];
    if (t < 24) bs[t] = hb[t];
    __syncthreads();
    int row = blockIdx.x * 256 + t;
    if (row >= MROWS) return;
    float acc[24];
    #pragma unroll
    for (int c = 0; c < 24; ++c) acc[c] = bs[c];
    const u16* a = &H3[(size_t)row * 128];
    for (int kq = 0; kq < 16; ++kq) {
        bf16x8 raw = *(const bf16x8*)&a[kq * 8];
        #pragma unroll
        for (int j = 0; j < 8; ++j) {
            float av = bf2f((u16)raw[j]);
            #pragma unroll
            for (int c = 0; c < 24; ++c)
                acc[c] = fmaf(av, Ws[(kq * 8 + j) * 24 + c], acc[c]);
        }
    }
    int n = row >> 3, b = row & 7;
    #pragma unroll
    for (int tt = 0; tt < 12; ++tt) {
        float2 o;
        o.x = acc[tt * 2 + 0];
        o.y = acc[tt * 2 + 1];
        *(float2*)&out[((b * TIN + tt) * NNODE + n) * 2] = o;
    }
}

// ---------------------------------------------------------------------------
extern "C" void kernel_launch(void* const* d_in, const int* in_sizes, int n_in,
                              void* d_out, int out_size, void* d_ws, size_t ws_size,
                              hipStream_t stream) {
    const float* x      = (const float*)d_in[0];
    const int*   ei     = (const int*)d_in[1];
    const float* Wl0    = (const float*)d_in[2];
    const float* Wr0    = (const float*)d_in[3];
    const float* bl0    = (const float*)d_in[4];
    const float* Wl12   = (const float*)d_in[5];
    const float* Wr12   = (const float*)d_in[6];
    const float* bl12   = (const float*)d_in[7];
    const float* bn_g   = (const float*)d_in[8];
    const float* bn_b   = (const float*)d_in[9];
    const float* bn_m   = (const float*)d_in[10];
    const float* bn_v   = (const float*)d_in[11];
    const float* headW  = (const float*)d_in[12];
    const float* headb  = (const float*)d_in[13];
    float* out = (float*)d_out;

    u16* X0 = (u16*)d_ws;                            // M x 64 row-major
    u16* X1 = X0 + (size_t)MROWS * 64;               // [16][M][16] chunked
    u16* X2 = X1 + (size_t)MROWS * 256;              // [16][M][16] chunked
    u16* W0T = X2 + (size_t)MROWS * 256;             // 128 x 64
    u16* W1T = W0T + 128 * 64;                       // 128 x 256
    u16* W2T = W1T + 128 * 256;                      // 128 x 256
    float* bias012 = (float*)(W2T + 128 * 256);      // 3 x 128
    float* inv_deg = bias012 + 3 * 128;              // N
    int* degi    = (int*)(inv_deg + NNODE);          // N
    int* row_ptr = degi + NNODE;                     // N+1
    int* cursor  = row_ptr + (NNODE + 1);            // N
    int* csr_src = cursor + NNODE;                   // E
    u16* H3 = X1;                                    // alias (X1 dead after gemm1)

    hipMemsetAsync(degi, 0, sizeof(int) * NNODE, stream);

    fused_pre<<<4503, 256, 0, stream>>>(x, X0, ei, degi, Wl0, Wr0, bl0, Wl12, Wr12,
                                        bl12, bn_g, bn_b, bn_m, bn_v,
                                        W0T, W1T, W2T, bias012);
    scan_kernel<<<1, 1024, 0, stream>>>(degi, row_ptr, inv_deg, cursor);
    csr_fill<<<(NEDGE + 255) / 256, 256, 0, stream>>>(ei, row_ptr, cursor, csr_src);

    // layer 0
    agg24<<<NNODE / 2, 192, 0, stream>>>(X0, row_ptr, csr_src, inv_deg);
    gemm_mfma<64, false, true><<<250, 640, 0, stream>>>(X0, W0T, bias012, X1);
    // layer 1
    agg128c<<<NNODE * 8, 64, 0, stream>>>(X1, row_ptr, csr_src, inv_deg);
    gemm_mfma<256, true, true><<<250, 640, 0, stream>>>(X1, W1T, bias012 + 128, X2);
    // layer 2
    agg128c<<<NNODE * 8, 64, 0, stream>>>(X2, row_ptr, csr_src, inv_deg);
    gemm_mfma<256, true, false><<<250, 640, 0, stream>>>(X2, W2T, bias012 + 256, H3);
    // head
    head_kernel<<<(MROWS + 255) / 256, 256, 0, stream>>>(H3, headW, headb, out);
}

// Round 7
// 248.495 us; speedup vs baseline: 2.2084x; 1.1392x over previous
//
#include <hip/hip_runtime.h>

#define NB 8
#define NNODE 10000
#define NEDGE 160000
#define MROWS 80000
#define TIN 12
#define EPSBN 1e-5f

typedef __attribute__((ext_vector_type(8))) short bf16x8;
typedef __attribute__((ext_vector_type(4))) float f32x4;
typedef unsigned short u16;
typedef unsigned int u32;

static __device__ __forceinline__ u16 f2bf(float f) {
    unsigned int u = __builtin_bit_cast(unsigned int, f);
    u = (u + 0x7fffu + ((u >> 16) & 1u)) >> 16;
    return (u16)u;
}
static __device__ __forceinline__ float bf2f(u16 h) {
    unsigned int u = ((unsigned int)h) << 16;
    return __builtin_bit_cast(float, u);
}

// ---------------------------------------------------------------------------
// fused pre-stage: [0,313) transpose_x (row/thread) | [313,938) deg | [938,1066) prep
__global__ __launch_bounds__(256) void fused_pre(const float* __restrict__ x,
                                                 u16* __restrict__ X0,
                                                 const int* __restrict__ ei,
                                                 int* __restrict__ degi,
                                                 const float* __restrict__ Wl0,
                                                 const float* __restrict__ Wr0,
                                                 const float* __restrict__ bl0,
                                                 const float* __restrict__ Wl12,
                                                 const float* __restrict__ Wr12,
                                                 const float* __restrict__ bl12,
                                                 const float* __restrict__ g,
                                                 const float* __restrict__ bb,
                                                 const float* __restrict__ m,
                                                 const float* __restrict__ v,
                                                 u16* __restrict__ W0T, u16* __restrict__ W1T,
                                                 u16* __restrict__ W2T,
                                                 float* __restrict__ bias012) {
    int blk = blockIdx.x;
    if (blk < 313) {
        int row = blk * 256 + threadIdx.x;        // row = n*8 + b
        if (row >= MROWS) return;
        int n = row >> 3, b = row & 7;
        u32 w[12];
        #pragma unroll
        for (int tt = 0; tt < 12; ++tt) {
            float2 vv = *(const float2*)&x[(size_t)((b * 12 + tt) * NNODE + n) * 2];
            w[tt] = (u32)f2bf(vv.x) | ((u32)f2bf(vv.y) << 16);
        }
        u32* dst = (u32*)&X0[(size_t)row * 48 + 24];   // h at cols 24..47, 16B aligned
        *(uint4*)(dst + 0) = make_uint4(w[0], w[1], w[2], w[3]);
        *(uint4*)(dst + 4) = make_uint4(w[4], w[5], w[6], w[7]);
        *(uint4*)(dst + 8) = make_uint4(w[8], w[9], w[10], w[11]);
    } else if (blk < 938) {
        int e = (blk - 313) * 256 + threadIdx.x;
        if (e < NEDGE) atomicAdd(&degi[ei[NEDGE + e]], 1);
    } else {
        int c = blk - 938, k = threadIdx.x;
        float s0 = g[c] / sqrtf(v[c] + EPSBN);
        float s1 = g[128 + c] / sqrtf(v[128 + c] + EPSBN);
        float s2 = g[256 + c] / sqrtf(v[256 + c] + EPSBN);
        if (k < 64) {
            float val = (k < 24) ? Wl0[k * 128 + c] : ((k < 48) ? Wr0[(k - 24) * 128 + c] : 0.0f);
            W0T[c * 64 + k] = f2bf(val * s0);
        }
        float v1 = (k < 128) ? Wl12[k * 128 + c] : Wr12[(k - 128) * 128 + c];
        W1T[c * 256 + k] = f2bf(v1 * s1);
        float v2 = (k < 128) ? Wl12[128 * 128 + k * 128 + c]
                             : Wr12[128 * 128 + (k - 128) * 128 + c];
        W2T[c * 256 + k] = f2bf(v2 * s2);
        if (k < 3) {
            float sl = g[k * 128 + c] / sqrtf(v[k * 128 + c] + EPSBN);
            float blv = (k == 0) ? bl0[c] : bl12[(k - 1) * 128 + c];
            bias012[k * 128 + c] = blv * sl + bb[k * 128 + c] - m[k * 128 + c] * sl;
        }
    }
}

// prefix scan over deg -> row_ptr, inv_deg; also zeroes cursor
__global__ __launch_bounds__(1024) void scan_kernel(const int* __restrict__ degi,
                                                    int* __restrict__ row_ptr,
                                                    float* __restrict__ inv_deg,
                                                    int* __restrict__ cursor) {
    __shared__ int sdata[1024];
    const int t = threadIdx.x;
    const int CH = 10;
    const int i0 = t * CH;
    int sum = 0;
    for (int i = i0; i < i0 + CH && i < NNODE; ++i) sum += degi[i];
    sdata[t] = sum;
    for (int off = 1; off < 1024; off <<= 1) {
        __syncthreads();
        int vv = (t >= off) ? sdata[t - off] : 0;
        __syncthreads();
        sdata[t] += vv;
    }
    __syncthreads();
    int run = sdata[t] - sum;
    for (int i = i0; i < i0 + CH && i < NNODE; ++i) {
        row_ptr[i] = run;
        int d = degi[i];
        run += d;
        inv_deg[i] = 1.0f / (float)max(d, 1);
        cursor[i] = 0;
    }
    if (t == 1023) row_ptr[NNODE] = sdata[1023];
}

__global__ void csr_fill(const int* __restrict__ ei, const int* __restrict__ row_ptr,
                         int* __restrict__ cursor, int* __restrict__ csr_src) {
    int e = blockIdx.x * blockDim.x + threadIdx.x;
    if (e < NEDGE) {
        int d = ei[NEDGE + e];
        int pos = atomicAdd(&cursor[d], 1);
        csr_src[row_ptr[d] + pos] = ei[e];
    }
}

// mean-aggregation K=24 on row-major X0 (stride 48), 2 nodes/block, unroll-4
__global__ __launch_bounds__(192) void agg24(u16* __restrict__ X0,
                                             const int* __restrict__ rp,
                                             const int* __restrict__ cs,
                                             const float* __restrict__ inv) {
    int u = threadIdx.x;
    int n = blockIdx.x * 2 + (u / 96);
    int w = u % 96;
    int b = w / 12, cp = w % 12;
    int p0 = rp[n], p1 = rp[n + 1];
    float a0 = 0, a1 = 0, b0 = 0, b1 = 0, c0 = 0, c1 = 0, d0 = 0, d1 = 0;
    int p = p0;
    for (; p + 4 <= p1; p += 4) {
        int s0 = cs[p], s1 = cs[p + 1], s2 = cs[p + 2], s3 = cs[p + 3];
        u32 v0 = *(const u32*)&X0[(s0 * NB + b) * 48 + 24 + cp * 2];
        u32 v1 = *(const u32*)&X0[(s1 * NB + b) * 48 + 24 + cp * 2];
        u32 v2 = *(const u32*)&X0[(s2 * NB + b) * 48 + 24 + cp * 2];
        u32 v3 = *(const u32*)&X0[(s3 * NB + b) * 48 + 24 + cp * 2];
        a0 += bf2f((u16)(v0 & 0xffff)); a1 += bf2f((u16)(v0 >> 16));
        b0 += bf2f((u16)(v1 & 0xffff)); b1 += bf2f((u16)(v1 >> 16));
        c0 += bf2f((u16)(v2 & 0xffff)); c1 += bf2f((u16)(v2 >> 16));
        d0 += bf2f((u16)(v3 & 0xffff)); d1 += bf2f((u16)(v3 >> 16));
    }
    for (; p < p1; ++p) {
        int s = cs[p];
        u32 vv = *(const u32*)&X0[(s * NB + b) * 48 + 24 + cp * 2];
        a0 += bf2f((u16)(vv & 0xffff)); a1 += bf2f((u16)(vv >> 16));
    }
    float sc = inv[n];
    float r0 = (a0 + b0) + (c0 + d0), r1 = (a1 + b1) + (c1 + d1);
    u32 o = (u32)f2bf(r0 * sc) | ((u32)f2bf(r1 * sc) << 16);
    *(u32*)&X0[(n * NB + b) * 48 + cp * 2] = o;
}

// chunked mean-aggregation K=128: X layout [16 chunks][MROWS][16 cols],
// h in chunks 8..15, mean -> chunks 0..7. chunk = blockIdx&7 (XCD-pinned), unroll-4.
__global__ __launch_bounds__(64) void agg128c(u16* __restrict__ X,
                                              const int* __restrict__ rp,
                                              const int* __restrict__ cs,
                                              const float* __restrict__ inv) {
    int bid = blockIdx.x;
    int c = bid & 7;
    int n = bid >> 3;
    int t = threadIdx.x;
    int b = t >> 3, q = t & 7;
    int p0 = rp[n], p1 = rp[n + 1];
    const u16* hb = X + ((size_t)(8 + c) * MROWS) * 16;
    float a0 = 0, a1 = 0, b0 = 0, b1 = 0, c0 = 0, c1 = 0, d0 = 0, d1 = 0;
    int p = p0;
    for (; p + 4 <= p1; p += 4) {
        int s0 = cs[p], s1 = cs[p + 1], s2 = cs[p + 2], s3 = cs[p + 3];
        u32 v0 = *(const u32*)&hb[(s0 * NB + b) * 16 + q * 2];
        u32 v1 = *(const u32*)&hb[(s1 * NB + b) * 16 + q * 2];
        u32 v2 = *(const u32*)&hb[(s2 * NB + b) * 16 + q * 2];
        u32 v3 = *(const u32*)&hb[(s3 * NB + b) * 16 + q * 2];
        a0 += bf2f((u16)(v0 & 0xffff)); a1 += bf2f((u16)(v0 >> 16));
        b0 += bf2f((u16)(v1 & 0xffff)); b1 += bf2f((u16)(v1 >> 16));
        c0 += bf2f((u16)(v2 & 0xffff)); c1 += bf2f((u16)(v2 >> 16));
        d0 += bf2f((u16)(v3 & 0xffff)); d1 += bf2f((u16)(v3 >> 16));
    }
    for (; p < p1; ++p) {
        int s = cs[p];
        u32 vv = *(const u32*)&hb[(s * NB + b) * 16 + q * 2];
        a0 += bf2f((u16)(vv & 0xffff)); a1 += bf2f((u16)(vv >> 16));
    }
    float sc = inv[n];
    float r0 = (a0 + b0) + (c0 + d0), r1 = (a1 + b1) + (c1 + d1);
    u32 o = (u32)f2bf(r0 * sc) | ((u32)f2bf(r1 * sc) << 16);
    *(u32*)&X[((size_t)c * MROWS + n * NB + b) * 16 + q * 2] = o;
}

// MFMA GEMM, M-tile 320 x N 128, 10 waves, W staged in LDS once, A direct
// global->VGPR with depth-1 prefetch. HEAD: fused 128->24 projection + scatter.
#define LOADA(dst, stp) { \
    const int k0_ = (stp) * 32 + kg * 8; \
    _Pragma("unroll") \
    for (int m_ = 0; m_ < 4; ++m_) { \
        const int row_ = rowbase + m_ * 16; \
        const u16* ap_; \
        if (INC) ap_ = A + ((size_t)(k0_ >> 4) * MROWS + row_) * 16 + (k0_ & 15); \
        else     ap_ = A + (size_t)row_ * LDA + k0_; \
        dst[m_] = *(const bf16x8*)ap_; \
    } }

#define MFMAS(av, stp) { \
    const int k0_ = (stp) * 32 + kg * 8; \
    bf16x8 bv_[4]; \
    _Pragma("unroll") \
    for (int n_ = 0; n_ < 4; ++n_) \
        bv_[n_] = *(const bf16x8*)&Bs[wc * 64 + n_ * 16 + r16][k0_]; \
    _Pragma("unroll") \
    for (int m_ = 0; m_ < 4; ++m_) \
        _Pragma("unroll") \
        for (int n_ = 0; n_ < 4; ++n_) \
            acc[m_][n_] = __builtin_amdgcn_mfma_f32_16x16x32_bf16(av[m_], bv_[n_], acc[m_][n_], 0, 0, 0); }

template<int K, int LDA, bool INC, bool HEAD>
__global__ __launch_bounds__(640) void gemm_mfma(const u16* __restrict__ A,
                                                 const u16* __restrict__ WT,
                                                 const float* __restrict__ bias,
                                                 const float* __restrict__ hW,
                                                 const float* __restrict__ hb,
                                                 u16* __restrict__ outc,
                                                 float* __restrict__ outf) {
    constexpr int NSTEP = K / 32;
    constexpr int BS_BYTES = 128 * (K + 8) * 2;
    constexpr int HS_BYTES = 320 * 132 * 2;                     // 84480
    constexpr int SMEM_BYTES = HEAD ? (HS_BYTES + 128 * 24 * 4 + 128) : BS_BYTES;
    __shared__ __align__(16) char smem[SMEM_BYTES];
    typedef short (*BsT)[K + 8];
    BsT Bs = (BsT)smem;

    const int t = threadIdx.x;
    const int row0 = blockIdx.x * 320;
    const int lane = t & 63, wid = t >> 6;
    const int wr = wid >> 1, wc = wid & 1;
    const int r16 = lane & 15, kg = lane >> 4;

    float* Wsf = (float*)(smem + HS_BYTES);        // head W [128][24] fp32
    float* bsh = Wsf + 128 * 24;                   // head bias [24]
    if (HEAD) {
        for (int i = t; i < 128 * 24; i += 640) Wsf[i] = hW[i];
        if (t < 24) bsh[t] = hb[t];
    }
    if (t < 512) {
        const int col = t >> 2, k0 = (t & 3) * (K / 4);
        #pragma unroll
        for (int j = 0; j < K / 32; ++j)
            *(bf16x8*)&Bs[col][k0 + j * 8] =
                *(const bf16x8*)&WT[col * K + k0 + j * 8];
    }
    __syncthreads();

    f32x4 acc[4][4];
    #pragma unroll
    for (int m = 0; m < 4; ++m)
        #pragma unroll
        for (int n = 0; n < 4; ++n)
            acc[m][n] = (f32x4){0.f, 0.f, 0.f, 0.f};

    const int rowbase = row0 + wr * 64 + r16;

    bf16x8 avA[4], avB[4];
    LOADA(avA, 0)
    #pragma unroll
    for (int s2 = 0; s2 < NSTEP; s2 += 2) {
        if (s2 + 1 < NSTEP) LOADA(avB, s2 + 1)
        MFMAS(avA, s2)
        if (s2 + 2 < NSTEP) LOADA(avA, s2 + 2)
        if (s2 + 1 < NSTEP) MFMAS(avB, s2 + 1)
    }

    if (!HEAD) {
        #pragma unroll
        for (int m = 0; m < 4; ++m)
            #pragma unroll
            for (int n = 0; n < 4; ++n) {
                int col = wc * 64 + n * 16 + r16;
                float bvf = bias[col];
                #pragma unroll
                for (int r = 0; r < 4; ++r) {
                    int grow = row0 + wr * 64 + m * 16 + kg * 4 + r;
                    float val = fmaxf(acc[m][n][r] + bvf, 0.0f);
                    outc[((size_t)(8 + wc * 4 + n) * MROWS + grow) * 16 + r16] = f2bf(val);
                }
            }
    } else {
        // stage relu'd h3 tile into LDS (reuses Bs region), then fused head
        __syncthreads();                           // all waves done reading Bs
        u16* Hs = (u16*)smem;                      // [320][132]
        #pragma unroll
        for (int m = 0; m < 4; ++m)
            #pragma unroll
            for (int n = 0; n < 4; ++n) {
                int col = wc * 64 + n * 16 + r16;
                float bvf = bias[col];
                #pragma unroll
                for (int r = 0; r < 4; ++r) {
                    int lrow = wr * 64 + m * 16 + kg * 4 + r;
                    Hs[lrow * 132 + col] = f2bf(fmaxf(acc[m][n][r] + bvf, 0.0f));
                }
            }
        __syncthreads();
        // head: 2 threads per row, 12 outputs each
        int lrow = t >> 1, half = t & 1;
        const u32* hrow = (const u32*)(Hs + lrow * 132);
        const float* wbase = Wsf + half * 12;
        float a24[12];
        #pragma unroll
        for (int j = 0; j < 12; ++j) a24[j] = bsh[half * 12 + j];
        #pragma unroll 4
        for (int kq = 0; kq < 64; ++kq) {
            u32 wv = hrow[kq];
            float f0 = bf2f((u16)(wv & 0xffff));
            float f1 = bf2f((u16)(wv >> 16));
            const float* w0 = wbase + (kq * 2) * 24;
            #pragma unroll
            for (int j = 0; j < 12; ++j)
                a24[j] = fmaf(f0, w0[j], a24[j]);
            const float* w1 = wbase + (kq * 2 + 1) * 24;
            #pragma unroll
            for (int j = 0; j < 12; ++j)
                a24[j] = fmaf(f1, w1[j], a24[j]);
        }
        int grow = row0 + lrow;
        int n = grow >> 3, b = grow & 7;
        #pragma unroll
        for (int jj = 0; jj < 12; jj += 2) {
            int tt = (half * 12 + jj) >> 1;
            float2 o = {a24[jj], a24[jj + 1]};
            *(float2*)&outf[((size_t)(b * TIN + tt) * NNODE + n) * 2] = o;
        }
    }
}

// ---------------------------------------------------------------------------
extern "C" void kernel_launch(void* const* d_in, const int* in_sizes, int n_in,
                              void* d_out, int out_size, void* d_ws, size_t ws_size,
                              hipStream_t stream) {
    const float* x      = (const float*)d_in[0];
    const int*   ei     = (const int*)d_in[1];
    const float* Wl0    = (const float*)d_in[2];
    const float* Wr0    = (const float*)d_in[3];
    const float* bl0    = (const float*)d_in[4];
    const float* Wl12   = (const float*)d_in[5];
    const float* Wr12   = (const float*)d_in[6];
    const float* bl12   = (const float*)d_in[7];
    const float* bn_g   = (const float*)d_in[8];
    const float* bn_b   = (const float*)d_in[9];
    const float* bn_m   = (const float*)d_in[10];
    const float* bn_v   = (const float*)d_in[11];
    const float* headW  = (const float*)d_in[12];
    const float* headb  = (const float*)d_in[13];
    float* out = (float*)d_out;

    u16* X0 = (u16*)d_ws;                            // M x 48 row-major (+32 slack)
    u16* X1 = X0 + (size_t)MROWS * 48 + 32;          // [16][M][16] chunked
    u16* X2 = X1 + (size_t)MROWS * 256;              // [16][M][16] chunked
    u16* W0T = X2 + (size_t)MROWS * 256;             // 128 x 64 (rows 48..63 zero)
    u16* W1T = W0T + 128 * 64;                       // 128 x 256
    u16* W2T = W1T + 128 * 256;                      // 128 x 256
    float* bias012 = (float*)(W2T + 128 * 256);      // 3 x 128
    float* inv_deg = bias012 + 3 * 128;              // N
    int* degi    = (int*)(inv_deg + NNODE);          // N
    int* row_ptr = degi + NNODE;                     // N+1
    int* cursor  = row_ptr + (NNODE + 1);            // N
    int* csr_src = cursor + NNODE;                   // E

    hipMemsetAsync(degi, 0, sizeof(int) * NNODE, stream);

    fused_pre<<<1066, 256, 0, stream>>>(x, X0, ei, degi, Wl0, Wr0, bl0, Wl12, Wr12,
                                        bl12, bn_g, bn_b, bn_m, bn_v,
                                        W0T, W1T, W2T, bias012);
    scan_kernel<<<1, 1024, 0, stream>>>(degi, row_ptr, inv_deg, cursor);
    csr_fill<<<(NEDGE + 255) / 256, 256, 0, stream>>>(ei, row_ptr, cursor, csr_src);

    // layer 0
    agg24<<<NNODE / 2, 192, 0, stream>>>(X0, row_ptr, csr_src, inv_deg);
    gemm_mfma<64, 48, false, false><<<250, 640, 0, stream>>>(X0, W0T, bias012,
                                                             nullptr, nullptr, X1, nullptr);
    // layer 1
    agg128c<<<NNODE * 8, 64, 0, stream>>>(X1, row_ptr, csr_src, inv_deg);
    gemm_mfma<256, 0, true, false><<<250, 640, 0, stream>>>(X1, W1T, bias012 + 128,
                                                            nullptr, nullptr, X2, nullptr);
    // layer 2 + fused head
    agg128c<<<NNODE * 8, 64, 0, stream>>>(X2, row_ptr, csr_src, inv_deg);
    gemm_mfma<256, 0, true, true><<<250, 640, 0, stream>>>(X2, W2T, bias012 + 256,
                                                           headW, headb, nullptr, out);
}